// Round 8
// baseline (56.628 us; speedup 1.0000x reference)
//
#include <hip/hip_runtime.h>

#define DPROJ 1024

typedef short  bf16x8 __attribute__((ext_vector_type(8)));
typedef float  f32x4  __attribute__((ext_vector_type(4)));
typedef unsigned short u16x4 __attribute__((ext_vector_type(4)));

__device__ __forceinline__ unsigned short f2bf(float f) {
  unsigned u = __builtin_bit_cast(unsigned, f);
  u += 0x7FFFu + ((u >> 16) & 1u);          // round-to-nearest-even
  return (unsigned short)(u >> 16);
}

__device__ __forceinline__ bf16x8 pack8(float4 lo, float4 hi) {
  bf16x8 r;
  r[0] = (short)f2bf(lo.x); r[1] = (short)f2bf(lo.y);
  r[2] = (short)f2bf(lo.z); r[3] = (short)f2bf(lo.w);
  r[4] = (short)f2bf(hi.x); r[5] = (short)f2bf(hi.y);
  r[6] = (short)f2bf(hi.z); r[7] = (short)f2bf(hi.w);
  return r;
}

// ---------------------------------------------------------------------------
// Kernel 0: zero the 4 bucket counters (replaces hipMemsetAsync -- keeps the
// profile clean and the graph free of fillBuffer nodes).
// ---------------------------------------------------------------------------
__global__ void zero_counts(int* __restrict__ counts) {
  if (threadIdx.x < 4) counts[threadIdx.x] = 0;
}

// ---------------------------------------------------------------------------
// Kernel 1: classify tokens into 4 bucket lists. Entry packs (in-bucket row
// << 14) | token_id. Wave-aggregated atomics. List order nondeterministic but
// every token's output value is position-independent -> output deterministic.
// ---------------------------------------------------------------------------
__global__ __launch_bounds__(256) void classify_kernel(const int* __restrict__ inp, int n,
                                                       int* __restrict__ counts,
                                                       unsigned* __restrict__ lists) {
  int t = blockIdx.x * 256 + threadIdx.x;
  int lane = threadIdx.x & 63;
  int v = (t < n) ? inp[t] : -1;
  int b = (v < 0) ? -1 : (v >= 200000) ? 3 : (v >= 40000) ? 2 : (v >= 20000) ? 1 : 0;
  int lo = (b == 3) ? 200000 : (b == 2) ? 40000 : (b == 1) ? 20000 : 0;
#pragma unroll
  for (int i = 0; i < 4; ++i) {
    unsigned long long m = __ballot(b == i);
    if (b == i) {
      int rank = __popcll(m & ((1ull << lane) - 1ull));
      int src  = __ffsll((unsigned long long)m) - 1;
      int base = 0;
      if (lane == src) base = atomicAdd(&counts[i], __popcll(m));
      base = __shfl(base, src);
      lists[i * n + base + rank] = ((unsigned)(v - lo) << 14) | (unsigned)t;
    }
  }
}

// ---------------------------------------------------------------------------
// Heavy path (D % 64 == 0): full-K, DOUBLE-BUFFERED LDS -> one barrier per
// chunk (vs two). Next chunk's 12 float4 loads are issued BEFORE the barrier,
// staying in flight across barrier + ds_read + MFMA; the ds_write (which
// needs them via vmcnt) runs after the MFMA phase. LDS bf16 tiles
// XOR-swizzled byte ^= (row&7)<<4 (G4: 128B rows else 16-way conflict on
// ds_read_b128).
// ---------------------------------------------------------------------------
template <int D>
__device__ __forceinline__ void gemm_heavy(const float* __restrict__ emb,
                                           const float* __restrict__ proj,
                                           const unsigned* __restrict__ list,
                                           int cnt, int r0,
                                           float* __restrict__ out, char* smem) {
  constexpr int NCH = D / 64;
  const int c0   = blockIdx.x * 128;
  const int tid  = threadIdx.x;
  const int lane = tid & 63;
  const int w    = tid >> 6;
  const int wr   = w >> 1, wc = w & 1;     // 2x2 wave grid: 32 rows x 64 cols
  const int lr   = lane & 15, t16 = lane >> 4;

  // buffer k: A at smem + k*24576 (8 KB), B at +8192 (16 KB)
  unsigned* toks = (unsigned*)(smem + 49152);

  if (tid < 64) {
    int p = r0 + tid;
    toks[tid] = (p < cnt) ? list[p] : 0u;   // pads -> row 0 (stores suppressed)
  }
  __syncthreads();

  // per-thread staging geometry (fixed across chunks)
  int ra[4], ca[4], cb[8], c4b[8];
#pragma unroll
  for (int i = 0; i < 4; ++i) {
    int q = tid + i * 256;
    ra[i] = q >> 4; ca[i] = (q & 15) * 4;
  }
#pragma unroll
  for (int i = 0; i < 8; ++i) {
    int q = tid + i * 256;
    cb[i] = q >> 4; c4b[i] = (q & 15) * 4;
  }
  const float* abase[4];
#pragma unroll
  for (int i = 0; i < 4; ++i)
    abase[i] = emb + (size_t)(toks[ra[i]] >> 14) * D + ca[i];
  const float* bbase[8];
#pragma unroll
  for (int i = 0; i < 8; ++i)
    bbase[i] = proj + (size_t)(c0 + cb[i]) * D + c4b[i];

  float4 arg[4], brg[8];
#pragma unroll
  for (int i = 0; i < 4; ++i) arg[i] = *reinterpret_cast<const float4*>(abase[i]);
#pragma unroll
  for (int i = 0; i < 8; ++i) brg[i] = *reinterpret_cast<const float4*>(bbase[i]);

  // prologue: stage chunk 0 into buffer 0
  {
    char* Ab = smem, *Bb = smem + 8192;
#pragma unroll
    for (int i = 0; i < 4; ++i) {
      u16x4 o = {f2bf(arg[i].x), f2bf(arg[i].y), f2bf(arg[i].z), f2bf(arg[i].w)};
      *reinterpret_cast<u16x4*>(Ab + ra[i] * 128 + ((ca[i] * 2) ^ ((ra[i] & 7) << 4))) = o;
    }
#pragma unroll
    for (int i = 0; i < 8; ++i) {
      u16x4 o = {f2bf(brg[i].x), f2bf(brg[i].y), f2bf(brg[i].z), f2bf(brg[i].w)};
      *reinterpret_cast<u16x4*>(Bb + cb[i] * 128 + ((c4b[i] * 2) ^ ((cb[i] & 7) << 4))) = o;
    }
  }

  f32x4 acc[2][4];
#pragma unroll
  for (int fi = 0; fi < 2; ++fi)
#pragma unroll
    for (int fj = 0; fj < 4; ++fj) acc[fi][fj] = (f32x4){0.f, 0.f, 0.f, 0.f};

  for (int ch = 0; ch < NCH; ++ch) {
    // issue NEXT chunk's loads before the barrier (in flight across
    // barrier + ds_read + MFMA; consumed by the ds_write below)
    if (ch + 1 < NCH) {
      const int k1 = (ch + 1) * 64;
#pragma unroll
      for (int i = 0; i < 4; ++i) arg[i] = *reinterpret_cast<const float4*>(abase[i] + k1);
#pragma unroll
      for (int i = 0; i < 8; ++i) brg[i] = *reinterpret_cast<const float4*>(bbase[i] + k1);
    }
    __syncthreads();                        // buf[ch&1] fully staged

    char* Ab = smem + (ch & 1) * 24576;
    char* Bb = Ab + 8192;
#pragma unroll
    for (int s = 0; s < 2; ++s) {
      bf16x8 a[2], b[4];
#pragma unroll
      for (int fi = 0; fi < 2; ++fi) {
        int row = wr * 32 + fi * 16 + lr;
        a[fi] = *reinterpret_cast<const bf16x8*>(
            Ab + row * 128 + ((s * 64 + t16 * 16) ^ ((row & 7) << 4)));
      }
#pragma unroll
      for (int fj = 0; fj < 4; ++fj) {
        int col = wc * 64 + fj * 16 + lr;
        b[fj] = *reinterpret_cast<const bf16x8*>(
            Bb + col * 128 + ((s * 64 + t16 * 16) ^ ((col & 7) << 4)));
      }
#pragma unroll
      for (int fi = 0; fi < 2; ++fi)
#pragma unroll
        for (int fj = 0; fj < 4; ++fj)
          acc[fi][fj] = __builtin_amdgcn_mfma_f32_16x16x32_bf16(a[fi], b[fj], acc[fi][fj], 0, 0, 0);
    }

    // stage chunk ch+1 into the other buffer (no one reads it this iter;
    // next iter's barrier publishes it)
    if (ch + 1 < NCH) {
      char* An = smem + ((ch + 1) & 1) * 24576;
      char* Bn = An + 8192;
#pragma unroll
      for (int i = 0; i < 4; ++i) {
        u16x4 o = {f2bf(arg[i].x), f2bf(arg[i].y), f2bf(arg[i].z), f2bf(arg[i].w)};
        *reinterpret_cast<u16x4*>(An + ra[i] * 128 + ((ca[i] * 2) ^ ((ra[i] & 7) << 4))) = o;
      }
#pragma unroll
      for (int i = 0; i < 8; ++i) {
        u16x4 o = {f2bf(brg[i].x), f2bf(brg[i].y), f2bf(brg[i].z), f2bf(brg[i].w)};
        *reinterpret_cast<u16x4*>(Bn + cb[i] * 128 + ((c4b[i] * 2) ^ ((cb[i] & 7) << 4))) = o;
      }
    }
  }
  __syncthreads();   // LDS safe for epilogue reuse

  // epilogue: transpose 16 rows x 64 cols per pass through per-wave LDS,
  // then float4 stores (256 B per quarter-wave). C/D frag: col = lane&15,
  // row = (lane>>4)*4 + reg (HW-verified).
  float* T = reinterpret_cast<float*>(smem + w * 4352);  // 16 x stride 68
#pragma unroll
  for (int fi = 0; fi < 2; ++fi) {
#pragma unroll
    for (int fj = 0; fj < 4; ++fj)
#pragma unroll
      for (int reg = 0; reg < 4; ++reg)
        T[(t16 * 4 + reg) * 68 + fj * 16 + lr] = acc[fi][fj][reg];
    // same-wave ds_write->ds_read ordering via compiler lgkmcnt
#pragma unroll
    for (int rr = 0; rr < 4; ++rr) {
      int p = wr * 32 + fi * 16 + rr * 4 + t16;
      if (r0 + p < cnt) {
        float4 v = *reinterpret_cast<const float4*>(&T[(rr * 4 + t16) * 68 + lr * 4]);
        *reinterpret_cast<float4*>(out + (size_t)(toks[p] & 16383u) * DPROJ +
                                   c0 + wc * 64 + lr * 4) = v;
      }
    }
  }
}

// ---------------------------------------------------------------------------
// Light path (D = 64 or 16, single K-chunk): no LDS staging -- load MFMA
// fragments direct from global (per lane: 8 k-contiguous f32 = 2 float4),
// convert in-register. One barrier total (toks).
// ---------------------------------------------------------------------------
template <int D>
__device__ __forceinline__ void gemm_light(const float* __restrict__ emb,
                                           const float* __restrict__ proj,
                                           const unsigned* __restrict__ list,
                                           int cnt, int r0,
                                           float* __restrict__ out, char* smem) {
  constexpr int S = (D == 64) ? 2 : 1;     // K=32 MFMA steps with real data
  const int c0   = blockIdx.x * 128;
  const int tid  = threadIdx.x;
  const int lane = tid & 63;
  const int w    = tid >> 6;
  const int wr   = w >> 1, wc = w & 1;
  const int lr   = lane & 15, t16 = lane >> 4;

  unsigned* toks = (unsigned*)smem;         // 64 entries
  if (tid < 64) {
    int p = r0 + tid;
    toks[tid] = (p < cnt) ? list[p] : 0u;
  }
  __syncthreads();

  bf16x8 a[2][S], b[4][S];
#pragma unroll
  for (int fi = 0; fi < 2; ++fi) {
    const float* eb = emb + (size_t)(toks[wr * 32 + fi * 16 + lr] >> 14) * D;
#pragma unroll
    for (int s = 0; s < S; ++s) {
      float4 lo = make_float4(0.f, 0.f, 0.f, 0.f), hi = lo;
      if (D == 64 || t16 < 2) {
        lo = *reinterpret_cast<const float4*>(eb + s * 32 + t16 * 8);
        hi = *reinterpret_cast<const float4*>(eb + s * 32 + t16 * 8 + 4);
      }
      a[fi][s] = pack8(lo, hi);
    }
  }
#pragma unroll
  for (int fj = 0; fj < 4; ++fj) {
    const float* pb = proj + (size_t)(c0 + wc * 64 + fj * 16 + lr) * D;
#pragma unroll
    for (int s = 0; s < S; ++s) {
      float4 lo = make_float4(0.f, 0.f, 0.f, 0.f), hi = lo;
      if (D == 64 || t16 < 2) {
        lo = *reinterpret_cast<const float4*>(pb + s * 32 + t16 * 8);
        hi = *reinterpret_cast<const float4*>(pb + s * 32 + t16 * 8 + 4);
      }
      b[fj][s] = pack8(lo, hi);
    }
  }

  f32x4 acc[2][4];
#pragma unroll
  for (int fi = 0; fi < 2; ++fi)
#pragma unroll
    for (int fj = 0; fj < 4; ++fj) acc[fi][fj] = (f32x4){0.f, 0.f, 0.f, 0.f};
#pragma unroll
  for (int s = 0; s < S; ++s)
#pragma unroll
    for (int fi = 0; fi < 2; ++fi)
#pragma unroll
      for (int fj = 0; fj < 4; ++fj)
        acc[fi][fj] = __builtin_amdgcn_mfma_f32_16x16x32_bf16(a[fi][s], b[fj][s], acc[fi][fj], 0, 0, 0);

  float* T = reinterpret_cast<float*>(smem + 256) + w * 1088;  // 16 x stride 68
#pragma unroll
  for (int fi = 0; fi < 2; ++fi) {
#pragma unroll
    for (int fj = 0; fj < 4; ++fj)
#pragma unroll
      for (int reg = 0; reg < 4; ++reg)
        T[(t16 * 4 + reg) * 68 + fj * 16 + lr] = acc[fi][fj][reg];
#pragma unroll
    for (int rr = 0; rr < 4; ++rr) {
      int p = wr * 32 + fi * 16 + rr * 4 + t16;
      if (r0 + p < cnt) {
        float4 v = *reinterpret_cast<const float4*>(&T[(rr * 4 + t16) * 68 + lr * 4]);
        *reinterpret_cast<float4*>(out + (size_t)(toks[p] & 16383u) * DPROJ +
                                   c0 + wc * 64 + lr * 4) = v;
      }
    }
  }
}

// ---------------------------------------------------------------------------
// Dispatcher. y segments: [b0 full-K][b1][b2][b3]; heavy work first.
// ---------------------------------------------------------------------------
__global__ __launch_bounds__(256) void gemm_all(
    const float* __restrict__ e0, const float* __restrict__ p0,
    const float* __restrict__ e1, const float* __restrict__ p1,
    const float* __restrict__ e2, const float* __restrict__ p2,
    const float* __restrict__ e3, const float* __restrict__ p3,
    const int* __restrict__ counts, const unsigned* __restrict__ lists,
    float* __restrict__ out, int n) {
  extern __shared__ char smem[];
  int4 c = *reinterpret_cast<const int4*>(counts);
  int t0 = (c.x + 63) >> 6, t1 = (c.y + 63) >> 6,
      t2 = (c.z + 63) >> 6, t3 = (c.w + 63) >> 6;
  int y = blockIdx.y;
  if (y < t0) { gemm_heavy<1024>(e0, p0, lists,               c.x, y * 64, out, smem); return; }
  y -= t0;
  if (y < t1) { gemm_heavy< 256>(e1, p1, lists + (size_t)n,   c.y, y * 64, out, smem); return; }
  y -= t1;
  if (y < t2) { gemm_light<64>(e2, p2, lists + (size_t)2 * n, c.z, y * 64, out, smem); return; }
  y -= t2;
  if (y < t3) { gemm_light<16>(e3, p3, lists + (size_t)3 * n, c.w, y * 64, out, smem); return; }
}

// ---------------------------------------------------------------------------
// Input order (setup_inputs dict order, verified rounds 1-7):
// inp, emb0, proj0, emb1, proj1, emb2, proj2, emb3, proj3.
// ws layout: [4 counts][4n packed lists].
// ---------------------------------------------------------------------------
extern "C" void kernel_launch(void* const* d_in, const int* in_sizes, int n_in,
                              void* d_out, int out_size, void* d_ws, size_t ws_size,
                              hipStream_t stream) {
  const int*   inp   = (const int*)d_in[0];
  const float* emb0  = (const float*)d_in[1];
  const float* proj0 = (const float*)d_in[2];
  const float* emb1  = (const float*)d_in[3];
  const float* proj1 = (const float*)d_in[4];
  const float* emb2  = (const float*)d_in[5];
  const float* proj2 = (const float*)d_in[6];
  const float* emb3  = (const float*)d_in[7];
  const float* proj3 = (const float*)d_in[8];
  float* out = (float*)d_out;
  const int n = in_sizes[0];  // 16384 tokens

  int*      counts = (int*)d_ws;
  unsigned* lists  = (unsigned*)d_ws + 4;

  zero_counts<<<dim3(1), dim3(64), 0, stream>>>(counts);
  classify_kernel<<<dim3((n + 255) / 256), dim3(256), 0, stream>>>(inp, n, counts, lists);

  // sum_i ceil(cnt_i/64) <= n/64 + 3 = 259 (nearly exact; few dead blocks)
  dim3 grid(DPROJ / 128, (n + 63) / 64 + 3, 1);
  size_t smem_bytes = 49152 + 64 * sizeof(unsigned);  // 49408 B -> 3 blocks/CU
  gemm_all<<<grid, dim3(256), smem_bytes, stream>>>(emb0, proj0, emb1, proj1,
                                                    emb2, proj2, emb3, proj3,
                                                    counts, lists, out, n);
}

// Round 9
// 52.558 us; speedup vs baseline: 1.0774x; 1.0774x over previous
//
#include <hip/hip_runtime.h>

#define DPROJ 1024

typedef short  bf16x8 __attribute__((ext_vector_type(8)));
typedef float  f32x4  __attribute__((ext_vector_type(4)));
typedef unsigned short u16x4 __attribute__((ext_vector_type(4)));

__device__ __forceinline__ unsigned short f2bf(float f) {
  unsigned u = __builtin_bit_cast(unsigned, f);
  u += 0x7FFFu + ((u >> 16) & 1u);          // round-to-nearest-even
  return (unsigned short)(u >> 16);
}

__device__ __forceinline__ bf16x8 pack8(float4 lo, float4 hi) {
  bf16x8 r;
  r[0] = (short)f2bf(lo.x); r[1] = (short)f2bf(lo.y);
  r[2] = (short)f2bf(lo.z); r[3] = (short)f2bf(lo.w);
  r[4] = (short)f2bf(hi.x); r[5] = (short)f2bf(hi.y);
  r[6] = (short)f2bf(hi.z); r[7] = (short)f2bf(hi.w);
  return r;
}

// ---------------------------------------------------------------------------
// Kernel 0: zero the 4 bucket counters (keeps graph free of fillBuffer nodes).
// ---------------------------------------------------------------------------
__global__ void zero_counts(int* __restrict__ counts) {
  if (threadIdx.x < 4) counts[threadIdx.x] = 0;
}

// ---------------------------------------------------------------------------
// Kernel 1: classify tokens into 4 bucket lists. Entry packs (in-bucket row
// << 14) | token_id. Wave-aggregated atomics. List order nondeterministic but
// every token's output value is position-independent -> output deterministic.
// ---------------------------------------------------------------------------
__global__ __launch_bounds__(256) void classify_kernel(const int* __restrict__ inp, int n,
                                                       int* __restrict__ counts,
                                                       unsigned* __restrict__ lists) {
  int t = blockIdx.x * 256 + threadIdx.x;
  int lane = threadIdx.x & 63;
  int v = (t < n) ? inp[t] : -1;
  int b = (v < 0) ? -1 : (v >= 200000) ? 3 : (v >= 40000) ? 2 : (v >= 20000) ? 1 : 0;
  int lo = (b == 3) ? 200000 : (b == 2) ? 40000 : (b == 1) ? 20000 : 0;
#pragma unroll
  for (int i = 0; i < 4; ++i) {
    unsigned long long m = __ballot(b == i);
    if (b == i) {
      int rank = __popcll(m & ((1ull << lane) - 1ull));
      int src  = __ffsll((unsigned long long)m) - 1;
      int base = 0;
      if (lane == src) base = atomicAdd(&counts[i], __popcll(m));
      base = __shfl(base, src);
      lists[i * n + base + rank] = ((unsigned)(v - lo) << 14) | (unsigned)t;
    }
  }
}

// ---------------------------------------------------------------------------
// Heavy path (D % 64 == 0): full-K, single LDS buffer, pipelined staging
// (next chunk's 12 float4 loads issued right after the barrier, in flight
// across ds_read+MFMA). LDS bf16 tiles XOR-swizzled byte ^= (row&7)<<4
// (G4: 128B rows else 16-way conflict on ds_read_b128).
// ---------------------------------------------------------------------------
template <int D>
__device__ __forceinline__ void gemm_heavy(const float* __restrict__ emb,
                                           const float* __restrict__ proj,
                                           const unsigned* __restrict__ list,
                                           int cnt, int r0, int c0,
                                           float* __restrict__ out, char* smem) {
  constexpr int NCH = D / 64;
  const int tid  = threadIdx.x;
  const int lane = tid & 63;
  const int w    = tid >> 6;
  const int wr   = w >> 1, wc = w & 1;     // 2x2 wave grid: 32 rows x 64 cols
  const int lr   = lane & 15, t16 = lane >> 4;

  char* Ab = smem;                          // A: 64 x 128 B  =  8 KB
  char* Bb = smem + 8192;                   // B: 128 x 128 B = 16 KB
  unsigned* toks = (unsigned*)(smem + 24576);

  if (tid < 64) {
    int p = r0 + tid;
    toks[tid] = (p < cnt) ? list[p] : 0u;   // pads -> row 0 (stores suppressed)
  }
  __syncthreads();

  // per-thread staging geometry (fixed across chunks)
  int ra[4], ca[4], cb[8], c4b[8];
#pragma unroll
  for (int i = 0; i < 4; ++i) {
    int q = tid + i * 256;
    ra[i] = q >> 4; ca[i] = (q & 15) * 4;
  }
#pragma unroll
  for (int i = 0; i < 8; ++i) {
    int q = tid + i * 256;
    cb[i] = q >> 4; c4b[i] = (q & 15) * 4;
  }
  const float* abase[4];
#pragma unroll
  for (int i = 0; i < 4; ++i)
    abase[i] = emb + (size_t)(toks[ra[i]] >> 14) * D + ca[i];
  const float* bbase[8];
#pragma unroll
  for (int i = 0; i < 8; ++i)
    bbase[i] = proj + (size_t)(c0 + cb[i]) * D + c4b[i];

  float4 arg[4], brg[8];
#pragma unroll
  for (int i = 0; i < 4; ++i) arg[i] = *reinterpret_cast<const float4*>(abase[i]);
#pragma unroll
  for (int i = 0; i < 8; ++i) brg[i] = *reinterpret_cast<const float4*>(bbase[i]);

  f32x4 acc[2][4];
#pragma unroll
  for (int fi = 0; fi < 2; ++fi)
#pragma unroll
    for (int fj = 0; fj < 4; ++fj) acc[fi][fj] = (f32x4){0.f, 0.f, 0.f, 0.f};

  for (int ch = 0; ch < NCH; ++ch) {
    // commit staged regs -> LDS (compiler inserts the vmcnt wait here)
#pragma unroll
    for (int i = 0; i < 4; ++i) {
      u16x4 o = {f2bf(arg[i].x), f2bf(arg[i].y), f2bf(arg[i].z), f2bf(arg[i].w)};
      *reinterpret_cast<u16x4*>(Ab + ra[i] * 128 + ((ca[i] * 2) ^ ((ra[i] & 7) << 4))) = o;
    }
#pragma unroll
    for (int i = 0; i < 8; ++i) {
      u16x4 o = {f2bf(brg[i].x), f2bf(brg[i].y), f2bf(brg[i].z), f2bf(brg[i].w)};
      *reinterpret_cast<u16x4*>(Bb + cb[i] * 128 + ((c4b[i] * 2) ^ ((cb[i] & 7) << 4))) = o;
    }
    __syncthreads();

    // issue NEXT chunk's loads now -- in flight across ds_read + MFMA + barrier
    if (ch + 1 < NCH) {
      const int k1 = (ch + 1) * 64;
#pragma unroll
      for (int i = 0; i < 4; ++i) arg[i] = *reinterpret_cast<const float4*>(abase[i] + k1);
#pragma unroll
      for (int i = 0; i < 8; ++i) brg[i] = *reinterpret_cast<const float4*>(bbase[i] + k1);
    }

#pragma unroll
    for (int s = 0; s < 2; ++s) {
      bf16x8 a[2], b[4];
#pragma unroll
      for (int fi = 0; fi < 2; ++fi) {
        int row = wr * 32 + fi * 16 + lr;
        a[fi] = *reinterpret_cast<const bf16x8*>(
            Ab + row * 128 + ((s * 64 + t16 * 16) ^ ((row & 7) << 4)));
      }
#pragma unroll
      for (int fj = 0; fj < 4; ++fj) {
        int col = wc * 64 + fj * 16 + lr;
        b[fj] = *reinterpret_cast<const bf16x8*>(
            Bb + col * 128 + ((s * 64 + t16 * 16) ^ ((col & 7) << 4)));
      }
#pragma unroll
      for (int fi = 0; fi < 2; ++fi)
#pragma unroll
        for (int fj = 0; fj < 4; ++fj)
          acc[fi][fj] = __builtin_amdgcn_mfma_f32_16x16x32_bf16(a[fi], b[fj], acc[fi][fj], 0, 0, 0);
    }
    __syncthreads();   // also makes LDS safe for next ds_write / epilogue
  }

  // epilogue: transpose 16 rows x 64 cols per pass through per-wave LDS,
  // then float4 stores (256 B per quarter-wave). C/D frag: col = lane&15,
  // row = (lane>>4)*4 + reg (HW-verified).
  float* T = reinterpret_cast<float*>(smem + w * 4352);  // 16 x stride 68
#pragma unroll
  for (int fi = 0; fi < 2; ++fi) {
#pragma unroll
    for (int fj = 0; fj < 4; ++fj)
#pragma unroll
      for (int reg = 0; reg < 4; ++reg)
        T[(t16 * 4 + reg) * 68 + fj * 16 + lr] = acc[fi][fj][reg];
    // same-wave ds_write->ds_read ordering via compiler lgkmcnt
#pragma unroll
    for (int rr = 0; rr < 4; ++rr) {
      int p = wr * 32 + fi * 16 + rr * 4 + t16;
      if (r0 + p < cnt) {
        float4 v = *reinterpret_cast<const float4*>(&T[(rr * 4 + t16) * 68 + lr * 4]);
        *reinterpret_cast<float4*>(out + (size_t)(toks[p] & 16383u) * DPROJ +
                                   c0 + wc * 64 + lr * 4) = v;
      }
    }
  }
}

// ---------------------------------------------------------------------------
// Light path (D = 64 or 16, single K-chunk): no LDS staging -- load MFMA
// fragments direct from global (per lane: 8 k-contiguous f32 = 2 float4),
// convert in-register. One barrier total (toks).
// ---------------------------------------------------------------------------
template <int D>
__device__ __forceinline__ void gemm_light(const float* __restrict__ emb,
                                           const float* __restrict__ proj,
                                           const unsigned* __restrict__ list,
                                           int cnt, int r0, int c0,
                                           float* __restrict__ out, char* smem) {
  constexpr int S = (D == 64) ? 2 : 1;     // K=32 MFMA steps with real data
  const int tid  = threadIdx.x;
  const int lane = tid & 63;
  const int w    = tid >> 6;
  const int wr   = w >> 1, wc = w & 1;
  const int lr   = lane & 15, t16 = lane >> 4;

  unsigned* toks = (unsigned*)smem;         // 64 entries
  if (tid < 64) {
    int p = r0 + tid;
    toks[tid] = (p < cnt) ? list[p] : 0u;
  }
  __syncthreads();

  bf16x8 a[2][S], b[4][S];
#pragma unroll
  for (int fi = 0; fi < 2; ++fi) {
    const float* eb = emb + (size_t)(toks[wr * 32 + fi * 16 + lr] >> 14) * D;
#pragma unroll
    for (int s = 0; s < S; ++s) {
      float4 lo = make_float4(0.f, 0.f, 0.f, 0.f), hi = lo;
      if (D == 64 || t16 < 2) {
        lo = *reinterpret_cast<const float4*>(eb + s * 32 + t16 * 8);
        hi = *reinterpret_cast<const float4*>(eb + s * 32 + t16 * 8 + 4);
      }
      a[fi][s] = pack8(lo, hi);
    }
  }
#pragma unroll
  for (int fj = 0; fj < 4; ++fj) {
    const float* pb = proj + (size_t)(c0 + wc * 64 + fj * 16 + lr) * D;
#pragma unroll
    for (int s = 0; s < S; ++s) {
      float4 lo = make_float4(0.f, 0.f, 0.f, 0.f), hi = lo;
      if (D == 64 || t16 < 2) {
        lo = *reinterpret_cast<const float4*>(pb + s * 32 + t16 * 8);
        hi = *reinterpret_cast<const float4*>(pb + s * 32 + t16 * 8 + 4);
      }
      b[fj][s] = pack8(lo, hi);
    }
  }

  f32x4 acc[2][4];
#pragma unroll
  for (int fi = 0; fi < 2; ++fi)
#pragma unroll
    for (int fj = 0; fj < 4; ++fj) acc[fi][fj] = (f32x4){0.f, 0.f, 0.f, 0.f};
#pragma unroll
  for (int s = 0; s < S; ++s)
#pragma unroll
    for (int fi = 0; fi < 2; ++fi)
#pragma unroll
      for (int fj = 0; fj < 4; ++fj)
        acc[fi][fj] = __builtin_amdgcn_mfma_f32_16x16x32_bf16(a[fi][s], b[fj][s], acc[fi][fj], 0, 0, 0);

  float* T = reinterpret_cast<float*>(smem + 256) + w * 1088;  // 16 x stride 68
#pragma unroll
  for (int fi = 0; fi < 2; ++fi) {
#pragma unroll
    for (int fj = 0; fj < 4; ++fj)
#pragma unroll
      for (int reg = 0; reg < 4; ++reg)
        T[(t16 * 4 + reg) * 68 + fj * 16 + lr] = acc[fi][fj][reg];
#pragma unroll
    for (int rr = 0; rr < 4; ++rr) {
      int p = wr * 32 + fi * 16 + rr * 4 + t16;
      if (r0 + p < cnt) {
        float4 v = *reinterpret_cast<const float4*>(&T[(rr * 4 + t16) * 68 + lr * 4]);
        *reinterpret_cast<float4*>(out + (size_t)(toks[p] & 16383u) * DPROJ +
                                   c0 + wc * 64 + lr * 4) = v;
      }
    }
  }
}

// ---------------------------------------------------------------------------
// Dispatcher. 1-D grid, XCD-grouping decode: the 8 col-slices of a row-tile
// have ids base(t)+8c -> all == t (mod 8) -> SAME XCD (round-robin m09) and
// within a 64-id span -> co-resident. Their writes merge to full 4 KB token
// rows in one L2; their identical A-gather reads hit the same L2.
// tile = (bx>>6)*8 + (bx&7); cslice = (bx>>3)&7.
// Tile segments: [b0][b1][b2][b3]; heavy tiles get lowest t -> dispatch first.
// ---------------------------------------------------------------------------
__global__ __launch_bounds__(256) void gemm_all(
    const float* __restrict__ e0, const float* __restrict__ p0,
    const float* __restrict__ e1, const float* __restrict__ p1,
    const float* __restrict__ e2, const float* __restrict__ p2,
    const float* __restrict__ e3, const float* __restrict__ p3,
    const int* __restrict__ counts, const unsigned* __restrict__ lists,
    float* __restrict__ out, int n) {
  extern __shared__ char smem[];
  int bx = blockIdx.x;
  int t  = ((bx >> 6) << 3) + (bx & 7);
  int c0 = ((bx >> 3) & 7) * 128;
  int4 c = *reinterpret_cast<const int4*>(counts);
  int t0 = (c.x + 63) >> 6, t1 = (c.y + 63) >> 6,
      t2 = (c.z + 63) >> 6, t3 = (c.w + 63) >> 6;
  if (t < t0) { gemm_heavy<1024>(e0, p0, lists,               c.x, t * 64, c0, out, smem); return; }
  t -= t0;
  if (t < t1) { gemm_heavy< 256>(e1, p1, lists + (size_t)n,   c.y, t * 64, c0, out, smem); return; }
  t -= t1;
  if (t < t2) { gemm_light<64>(e2, p2, lists + (size_t)2 * n, c.z, t * 64, c0, out, smem); return; }
  t -= t2;
  if (t < t3) { gemm_light<16>(e3, p3, lists + (size_t)3 * n, c.w, t * 64, c0, out, smem); return; }
}

// ---------------------------------------------------------------------------
// Input order (setup_inputs dict order, verified rounds 1-8):
// inp, emb0, proj0, emb1, proj1, emb2, proj2, emb3, proj3.
// ws layout: [4 counts][4n packed lists].
// ---------------------------------------------------------------------------
extern "C" void kernel_launch(void* const* d_in, const int* in_sizes, int n_in,
                              void* d_out, int out_size, void* d_ws, size_t ws_size,
                              hipStream_t stream) {
  const int*   inp   = (const int*)d_in[0];
  const float* emb0  = (const float*)d_in[1];
  const float* proj0 = (const float*)d_in[2];
  const float* emb1  = (const float*)d_in[3];
  const float* proj1 = (const float*)d_in[4];
  const float* emb2  = (const float*)d_in[5];
  const float* proj2 = (const float*)d_in[6];
  const float* emb3  = (const float*)d_in[7];
  const float* proj3 = (const float*)d_in[8];
  float* out = (float*)d_out;
  const int n = in_sizes[0];  // 16384 tokens

  int*      counts = (int*)d_ws;
  unsigned* lists  = (unsigned*)d_ws + 4;

  zero_counts<<<dim3(1), dim3(64), 0, stream>>>(counts);
  classify_kernel<<<dim3((n + 255) / 256), dim3(256), 0, stream>>>(inp, n, counts, lists);

  // tiles: sum_i ceil(cnt_i/64) <= n/64 + 3 = 259; pad to 264 (multiple of 8)
  // so the decode is bijective. 264 tiles x 8 col-slices = 2112 blocks.
  dim3 grid(264 * 8, 1, 1);
  size_t smem_bytes = 24576 + 64 * sizeof(unsigned);  // 24832 B -> 6 blocks/CU
  gemm_all<<<grid, dim3(256), smem_bytes, stream>>>(emb0, proj0, emb1, proj1,
                                                    emb2, proj2, emb3, proj3,
                                                    counts, lists, out, n);
}